// Round 12
// baseline (274.983 us; speedup 1.0000x reference)
//
#include <hip/hip_runtime.h>
#include <hip/hip_bf16.h>

#define N_NODES 50000
#define N_EDGES 800000
#define D_IN    1024
#define D_OUT   256
#define CAP     64
#define LEAKY   0.01f

typedef __attribute__((ext_vector_type(8))) short bf16x8;
typedef __attribute__((ext_vector_type(4))) float f32x4;
typedef __attribute__((ext_vector_type(4))) int   i32x4;
typedef unsigned short u16;

__device__ __forceinline__ u16 f2bfu(float f) {
  uint32_t x = __float_as_uint(f);
  uint32_t r = (x + 0x7FFFu + ((x >> 16) & 1u)) >> 16;  // RNE
  return (u16)r;
}
__device__ __forceinline__ float bfu2f(u16 u) {
  return __uint_as_float(((uint32_t)u) << 16);
}
// XOR bank swizzle for 128-B rows (measured 0 conflicts in r6/r8).
__device__ __forceinline__ int swz(int b) { return b ^ (((b >> 7) & 7) << 4); }

__device__ __forceinline__ void gll16(const void* g, void* l) {
  __builtin_amdgcn_global_load_lds(
      (const __attribute__((address_space(1))) uint32_t*)g,
      (__attribute__((address_space(3))) uint32_t*)l, 16, 0, 0);
}

// ---------------------------------------------------------------------------
// Kernel 1 (r6 version): weight fp32 [1024][256] -> bf16 swizzled image,
// 16 k-tiles x [256 n][64 k] x 32768 B. Also zeroes deg[]. Coalesced reads.
// ---------------------------------------------------------------------------
__global__ __launch_bounds__(256) void wconv_kernel(const float* __restrict__ w,
                                                    char* __restrict__ img,
                                                    int* __restrict__ deg) {
  const int t   = blockIdx.x * 256 + threadIdx.x;   // 0..32767
  if (t < N_NODES) deg[t] = 0;
  const int t2 = t + 32768;
  if (t2 < N_NODES) deg[t2] = 0;

  const int n   = t & 255;
  const int kc  = (t >> 8) * 8;
  const int kt  = kc >> 6;
  const int kin = kc & 63;
  bf16x8 v;
#pragma unroll
  for (int i = 0; i < 8; ++i) v[i] = (short)f2bfu(w[(size_t)(kc + i) * D_OUT + n]);
  *(bf16x8*)(img + kt * 32768 + swz(n * 128 + kin * 2)) = v;
}

// ---------------------------------------------------------------------------
// Kernel 2 (FUSED): 60 build blocks + 196 GEMM blocks = 256 (one per CU).
// GEMM = faithful 8-phase-template port: BM=256, BN=256(full), BK=64,
// 16 K-tiles, 8 waves (2n x 4m), per-wave 128n x 64m, acc[8][4].
// LDS: W[2][256][64] + X[2][256][64] bf16, both swizzled = 128 KB.
// Per K-tile, 4 phases of {ds_read quadrant | stage-issue -> barrier ->
// lgkmcnt(0) -> setprio(1) -> 16 MFMA -> setprio(0) -> barrier}.
// Aged vmcnt(0) once per tile at ph0 (everything outstanding is >=2 phases
// old: X loads issued 2 phases prior, W gll 4 phases prior).
// ---------------------------------------------------------------------------
#define BMg 256
#define GEMM_BLOCKS ((N_NODES + BMg - 1) / BMg)   // 196
#define BUILD_BLOCKS 60

__global__ __launch_bounds__(512) void gemm_build_kernel(
    const float* __restrict__ x, const char* __restrict__ img,
    u16* __restrict__ support,
    const int* __restrict__ ei, const float* __restrict__ ew,
    int* __restrict__ deg, int2* __restrict__ csr) {
  __shared__ u16 Wb[2][16384];   // [256 n][64 k] swizzled, 32 KB each
  __shared__ u16 Xb[2][16384];   // [256 m][64 k] swizzled, 32 KB each

  if (blockIdx.x < BUILD_BLOCKS) {
    const int t0 = blockIdx.x * 512 + threadIdx.x;
    for (int e = t0; e < N_EDGES; e += BUILD_BLOCKS * 512) {
      const int src = ei[e];
      const int dst = ei[N_EDGES + e];
      const float w = ew[e];
      const int slot = atomicAdd(&deg[dst], 1);
      if (slot < CAP) csr[dst * CAP + slot] = make_int2(src, __float_as_int(w));
    }
    return;
  }

  const int tid  = threadIdx.x;
  const int lane = tid & 63;
  const int wid  = tid >> 6;
  const int wn   = wid & 1;    // n-half (128 cols of W)
  const int wm   = wid >> 1;   // m-quarter (64 rows of X)
  const int l15  = lane & 15;
  const int l16  = lane >> 4;
  const int m0   = (blockIdx.x - BUILD_BLOCKS) * BMg;

  f32x4 acc[8][4];
#pragma unroll
  for (int i = 0; i < 8; ++i)
#pragma unroll
    for (int j = 0; j < 4; ++j) acc[i][j] = (f32x4)0.0f;

  // X staging: thread -> row = tid>>1 (0..255), k-half = (tid&1)*32 floats.
  const int xrow  = tid >> 1;
  const int xhalf = (tid & 1) * 32;
  const int xrg   = min(m0 + xrow, N_NODES - 1);
  const float* xp = x + (size_t)xrg * D_IN + xhalf;
  int xw[4];
#pragma unroll
  for (int j = 0; j < 4; ++j) xw[j] = swz(xrow * 128 + (xhalf + j * 8) * 2);

  // Fragment byte offsets.
  int a_off[2][8], b_off[2][4];
#pragma unroll
  for (int ks = 0; ks < 2; ++ks) {
#pragma unroll
    for (int nf = 0; nf < 8; ++nf)
      a_off[ks][nf] = swz((wn * 128 + nf * 16 + l15) * 128 + ks * 64 + l16 * 16);
#pragma unroll
    for (int mf = 0; mf < 4; ++mf)
      b_off[ks][mf] = swz((wm * 64 + mf * 16 + l15) * 128 + ks * 64 + l16 * 16);
  }

  f32x4 xs[8];     // one fp32 X set (32 floats), reused every iteration
  bf16x8 af[8];    // A (W) fragments, live across 2 phases

#define XLD(i0, tt) do {                                                   \
    const int kc_ = min((tt), 15);                                         \
    xs[i0]     = __builtin_nontemporal_load((const f32x4*)(xp + kc_ * 64));      \
    xs[i0 + 1] = __builtin_nontemporal_load((const f32x4*)(xp + kc_ * 64 + 4));  \
    xs[i0 + 2] = __builtin_nontemporal_load((const f32x4*)(xp + kc_ * 64 + 8));  \
    xs[i0 + 3] = __builtin_nontemporal_load((const f32x4*)(xp + kc_ * 64 + 12)); \
  } while (0)
  // note: XLD(0,..) loads floats [0..16), XLD(4,..) floats [16..32) -> adjust
#define XLD2(i0, tt, fo) do {                                              \
    const int kc_ = min((tt), 15);                                         \
    xs[i0]     = __builtin_nontemporal_load((const f32x4*)(xp + kc_ * 64 + (fo)));      \
    xs[i0 + 1] = __builtin_nontemporal_load((const f32x4*)(xp + kc_ * 64 + (fo) + 4));  \
    xs[i0 + 2] = __builtin_nontemporal_load((const f32x4*)(xp + kc_ * 64 + (fo) + 8));  \
    xs[i0 + 3] = __builtin_nontemporal_load((const f32x4*)(xp + kc_ * 64 + (fo) + 12)); \
  } while (0)

#define XCW(sl) do {                                                       \
    _Pragma("unroll")                                                      \
    for (int j_ = 0; j_ < 4; ++j_) {                                       \
      bf16x8 v_;                                                           \
      v_[0] = (short)f2bfu(xs[2 * j_][0]); v_[1] = (short)f2bfu(xs[2 * j_][1]); \
      v_[2] = (short)f2bfu(xs[2 * j_][2]); v_[3] = (short)f2bfu(xs[2 * j_][3]); \
      v_[4] = (short)f2bfu(xs[2 * j_ + 1][0]); v_[5] = (short)f2bfu(xs[2 * j_ + 1][1]); \
      v_[6] = (short)f2bfu(xs[2 * j_ + 1][2]); v_[7] = (short)f2bfu(xs[2 * j_ + 1][3]); \
      *(bf16x8*)((char*)&Xb[sl][0] + xw[j_]) = v_;                         \
    }                                                                      \
  } while (0)

#define GLLW(sl, tt) do {                                                  \
    const int kc_ = min((tt), 15);                                         \
    _Pragma("unroll")                                                      \
    for (int r_ = 0; r_ < 4; ++r_)                                         \
      gll16(img + kc_ * 32768 + r_ * 8192 + tid * 16,                      \
            (char*)&Wb[sl][0] + r_ * 8192 + tid * 16);                     \
  } while (0)

#define LDA(sl, ks) do {                                                   \
    _Pragma("unroll")                                                      \
    for (int nf_ = 0; nf_ < 8; ++nf_)                                      \
      af[nf_] = *(const bf16x8*)((const char*)&Wb[sl][0] + a_off[ks][nf_]); \
  } while (0)

#define MMQ(sl, ks, mp) do {                                               \
    bf16x8 bf0_ = *(const bf16x8*)((const char*)&Xb[sl][0] + b_off[ks][2 * (mp)]); \
    bf16x8 bf1_ = *(const bf16x8*)((const char*)&Xb[sl][0] + b_off[ks][2 * (mp) + 1]); \
    __builtin_amdgcn_s_barrier();                                          \
    asm volatile("s_waitcnt lgkmcnt(0)" ::: "memory");                     \
    __builtin_amdgcn_sched_barrier(0);                                     \
    __builtin_amdgcn_s_setprio(1);                                         \
    _Pragma("unroll")                                                      \
    for (int nf_ = 0; nf_ < 8; ++nf_) {                                    \
      acc[nf_][2 * (mp)]     = __builtin_amdgcn_mfma_f32_16x16x32_bf16(    \
          af[nf_], bf0_, acc[nf_][2 * (mp)], 0, 0, 0);                     \
      acc[nf_][2 * (mp) + 1] = __builtin_amdgcn_mfma_f32_16x16x32_bf16(    \
          af[nf_], bf1_, acc[nf_][2 * (mp) + 1], 0, 0, 0);                 \
    }                                                                      \
    __builtin_amdgcn_s_setprio(0);                                         \
    __builtin_amdgcn_s_barrier();                                          \
  } while (0)

  // One K-tile = 4 phases. cur/nxt are literal 0/1.
#define ITER(cur, nxt, T) do {                                             \
    /* ph0: aged drain; cvt+write X(T+1); gll W(T+1); quad(ks0,mf01) */    \
    asm volatile("s_waitcnt vmcnt(0)" ::: "memory");                       \
    __builtin_amdgcn_sched_barrier(0);                                     \
    XCW(nxt);                                                              \
    GLLW(nxt, (T) + 1);                                                    \
    LDA(cur, 0);                                                           \
    MMQ(cur, 0, 0);                                                        \
    /* ph1: issue X(T+2) lo; quad(ks0,mf23) */                             \
    XLD2(0, (T) + 2, 0);                                                   \
    MMQ(cur, 0, 1);                                                        \
    /* ph2: issue X(T+2) hi; quad(ks1,mf01) */                             \
    XLD2(4, (T) + 2, 16);                                                  \
    LDA(cur, 1);                                                           \
    MMQ(cur, 1, 0);                                                        \
    /* ph3: quad(ks1,mf23) */                                              \
    MMQ(cur, 1, 1);                                                        \
  } while (0)

  // ---- prologue ----
  XLD2(0, 0, 0);
  XLD2(4, 0, 16);
  asm volatile("s_waitcnt vmcnt(0)" ::: "memory");
  __builtin_amdgcn_sched_barrier(0);
  XCW(0);                       // Xb[0] <- tile 0
  GLLW(0, 0);                   // Wb[0] <- tile 0 (drained at T=0 ph0)
  XLD2(0, 1, 0);                // X(1) in regs
  XLD2(4, 1, 16);
  asm volatile("s_waitcnt lgkmcnt(0)" ::: "memory");
  __builtin_amdgcn_s_barrier();

  // ---- 16 K-tiles ----
  for (int T = 0; T < 16; T += 2) {
    ITER(0, 1, T);
    ITER(1, 0, T + 1);
  }

#undef XLD
#undef XLD2
#undef XCW
#undef GLLW
#undef LDA
#undef MMQ
#undef ITER

  // D: m = m0 + wm*64 + mf*16 + l15, n = wn*128 + nf*16 + l16*4 + reg.
#pragma unroll
  for (int mf = 0; mf < 4; ++mf) {
    const int m = m0 + wm * 64 + mf * 16 + l15;
    if (m < N_NODES) {
#pragma unroll
      for (int nf = 0; nf < 8; ++nf) {
        const int n = wn * 128 + nf * 16 + l16 * 4;
        ushort4 o;
        o.x = f2bfu(acc[nf][mf][0]);
        o.y = f2bfu(acc[nf][mf][1]);
        o.z = f2bfu(acc[nf][mf][2]);
        o.w = f2bfu(acc[nf][mf][3]);
        *(ushort4*)&support[(size_t)m * D_OUT + n] = o;
      }
    }
  }
}

// ---------------------------------------------------------------------------
// Kernel 3: per-node gather-aggregate + epilogue (r5 version, ~20 us).
// ---------------------------------------------------------------------------
__global__ __launch_bounds__(256) void agg_kernel(const u16* __restrict__ support,
                                                  const int* __restrict__ deg,
                                                  const int2* __restrict__ csr,
                                                  const float* __restrict__ norm,
                                                  const float* __restrict__ bias,
                                                  float* __restrict__ out) {
  const int lane = threadIdx.x & 63;
  const int wid  = threadIdx.x >> 6;
  const int node = blockIdx.x * 4 + wid;   // grid 12500 -> exactly 50000
  const int d    = min(deg[node], CAP);
  const int cb   = node * CAP;
  const int ch   = lane * 4;

  float a0 = 0.f, a1 = 0.f, a2 = 0.f, a3 = 0.f;
  int s = 0;

  for (; s + 16 <= d; s += 16) {
    i32x4 q[8];
#pragma unroll
    for (int i = 0; i < 8; ++i)
      q[i] = __builtin_nontemporal_load((const i32x4*)&csr[cb + s + 2 * i]);
    ushort4 v[16];
#pragma unroll
    for (int i = 0; i < 8; ++i) {
      v[2 * i]     = *(const ushort4*)&support[(size_t)q[i][0] * D_OUT + ch];
      v[2 * i + 1] = *(const ushort4*)&support[(size_t)q[i][2] * D_OUT + ch];
    }
#pragma unroll
    for (int i = 0; i < 8; ++i) {
      const float wa = __int_as_float(q[i][1]);
      const float wb = __int_as_float(q[i][3]);
      a0 = fmaf(wa, bfu2f(v[2 * i].x), a0);
      a1 = fmaf(wa, bfu2f(v[2 * i].y), a1);
      a2 = fmaf(wa, bfu2f(v[2 * i].z), a2);
      a3 = fmaf(wa, bfu2f(v[2 * i].w), a3);
      a0 = fmaf(wb, bfu2f(v[2 * i + 1].x), a0);
      a1 = fmaf(wb, bfu2f(v[2 * i + 1].y), a1);
      a2 = fmaf(wb, bfu2f(v[2 * i + 1].z), a2);
      a3 = fmaf(wb, bfu2f(v[2 * i + 1].w), a3);
    }
  }

  for (; s + 8 <= d; s += 8) {
    i32x4 q[4];
#pragma unroll
    for (int i = 0; i < 4; ++i)
      q[i] = __builtin_nontemporal_load((const i32x4*)&csr[cb + s + 2 * i]);
    ushort4 v[8];
#pragma unroll
    for (int i = 0; i < 4; ++i) {
      v[2 * i]     = *(const ushort4*)&support[(size_t)q[i][0] * D_OUT + ch];
      v[2 * i + 1] = *(const ushort4*)&support[(size_t)q[i][2] * D_OUT + ch];
    }
#pragma unroll
    for (int i = 0; i < 4; ++i) {
      const float wa = __int_as_float(q[i][1]);
      const float wb = __int_as_float(q[i][3]);
      a0 = fmaf(wa, bfu2f(v[2 * i].x), a0);
      a1 = fmaf(wa, bfu2f(v[2 * i].y), a1);
      a2 = fmaf(wa, bfu2f(v[2 * i].z), a2);
      a3 = fmaf(wa, bfu2f(v[2 * i].w), a3);
      a0 = fmaf(wb, bfu2f(v[2 * i + 1].x), a0);
      a1 = fmaf(wb, bfu2f(v[2 * i + 1].y), a1);
      a2 = fmaf(wb, bfu2f(v[2 * i + 1].z), a2);
      a3 = fmaf(wb, bfu2f(v[2 * i + 1].w), a3);
    }
  }

  for (; s < d; ++s) {
    const int2  e   = csr[cb + s];
    const float wgt = __int_as_float(e.y);
    const ushort4 v = *(const ushort4*)&support[(size_t)e.x * D_OUT + ch];
    a0 = fmaf(wgt, bfu2f(v.x), a0);
    a1 = fmaf(wgt, bfu2f(v.y), a1);
    a2 = fmaf(wgt, bfu2f(v.z), a2);
    a3 = fmaf(wgt, bfu2f(v.w), a3);
  }

  const float rn = 1.0f / norm[node];
  const float4 b = *(const float4*)&bias[ch];
  float o0 = fmaf(a0, rn, b.x);
  float o1 = fmaf(a1, rn, b.y);
  float o2 = fmaf(a2, rn, b.z);
  float o3 = fmaf(a3, rn, b.w);
  o0 = o0 > 0.f ? o0 : o0 * LEAKY;
  o1 = o1 > 0.f ? o1 : o1 * LEAKY;
  o2 = o2 > 0.f ? o2 : o2 * LEAKY;
  o3 = o3 > 0.f ? o3 : o3 * LEAKY;
  f32x4 ov;
  ov[0] = o0; ov[1] = o1; ov[2] = o2; ov[3] = o3;
  __builtin_nontemporal_store(ov, (f32x4*)&out[(size_t)node * D_OUT + ch]);
}

// ---------------------------------------------------------------------------
// ws layout (bytes):
//   support  bf16  [50000][256]     @ 0          25,600,000
//   Wimg     bf16  16x[256][64] swz @ 25,600,000    524,288
//   csr      int2  [50000][64]      @ 26,124,288 25,600,000
//   deg      int   [50000]          @ 51,724,288    200,000
// ---------------------------------------------------------------------------
extern "C" void kernel_launch(void* const* d_in, const int* in_sizes, int n_in,
                              void* d_out, int out_size, void* d_ws, size_t ws_size,
                              hipStream_t stream) {
  const float* x    = (const float*)d_in[0];
  const float* w    = (const float*)d_in[1];
  const float* bias = (const float*)d_in[2];
  const int*   ei   = (const int*)d_in[3];
  const float* ew   = (const float*)d_in[4];
  const float* norm = (const float*)d_in[5];
  float* out = (float*)d_out;

  char* ws = (char*)d_ws;
  u16*   support = (u16*)  (ws);
  char*  img     =         (ws + 25600000);
  int2*  csr     = (int2*) (ws + 26124288);
  int*   deg     = (int*)  (ws + 51724288);

  wconv_kernel<<<128, 256, 0, stream>>>(w, img, deg);
  gemm_build_kernel<<<BUILD_BLOCKS + GEMM_BLOCKS, 512, 0, stream>>>(
      x, img, support, ei, ew, deg, csr);
  agg_kernel<<<N_NODES / 4, 256, 0, stream>>>(support, deg, csr, norm, bias, out);
}

// Round 13
// 159.415 us; speedup vs baseline: 1.7249x; 1.7249x over previous
//
#include <hip/hip_runtime.h>
#include <hip/hip_bf16.h>

#define N_NODES 50000
#define N_EDGES 800000
#define D_IN    1024
#define D_OUT   256
#define CAP     64
#define LEAKY   0.01f

typedef __attribute__((ext_vector_type(8))) short bf16x8;
typedef __attribute__((ext_vector_type(4))) float f32x4;
typedef __attribute__((ext_vector_type(4))) int   i32x4;
typedef unsigned short u16;

__device__ __forceinline__ u16 f2bfu(float f) {
  uint32_t x = __float_as_uint(f);
  uint32_t r = (x + 0x7FFFu + ((x >> 16) & 1u)) >> 16;  // RNE
  return (u16)r;
}
__device__ __forceinline__ float bfu2f(u16 u) {
  return __uint_as_float(((uint32_t)u) << 16);
}
// XOR bank swizzle: flip byte bits 4-6 with row (byte>>7) low bits.
__device__ __forceinline__ int swz(int b) { return b ^ (((b >> 7) & 7) << 4); }

__device__ __forceinline__ void gll16(const void* g, void* l) {
  __builtin_amdgcn_global_load_lds(
      (const __attribute__((address_space(1))) uint32_t*)g,
      (__attribute__((address_space(3))) uint32_t*)l, 16, 0, 0);
}

// ---------------------------------------------------------------------------
// Kernel 1 (r6 version): weight fp32 [1024][256] -> bf16 swizzled image,
// 16 k-tiles x [256 n][64 k] x 32768 B. Also zeroes deg[]. Coalesced reads.
// ---------------------------------------------------------------------------
__global__ __launch_bounds__(256) void wconv_kernel(const float* __restrict__ w,
                                                    char* __restrict__ img,
                                                    int* __restrict__ deg) {
  const int t   = blockIdx.x * 256 + threadIdx.x;   // 0..32767
  if (t < N_NODES) deg[t] = 0;
  const int t2 = t + 32768;
  if (t2 < N_NODES) deg[t2] = 0;

  const int n   = t & 255;
  const int kc  = (t >> 8) * 8;
  const int kt  = kc >> 6;
  const int kin = kc & 63;
  bf16x8 v;
#pragma unroll
  for (int i = 0; i < 8; ++i) v[i] = (short)f2bfu(w[(size_t)(kc + i) * D_OUT + n]);
  *(bf16x8*)(img + kt * 32768 + swz(n * 128 + kin * 2)) = v;
}

// ---------------------------------------------------------------------------
// Kernel 2 (FUSED): r6's EXACT gemm (BM=64, BK=64, dbuf LDS, gll W) + build
// redistributed to ONE EDGE PER THREAD, interleaved with gemm blocks via
// blockIdx%3 (bid%3!=0 -> build, bid%3==0 -> gemm). 782 gemm + 1564 build
// = 2346 blocks. Diagnostic: if r6's ~121-us fused time was the grid-stride
// build path's 25 serialized contended atomics per thread (straggler), this
// drops the dispatch to the true gemm time; if the gemm is the pin, time is
// unchanged (and no worse than r6).
// ---------------------------------------------------------------------------
#define BM 64
#define BK 64
#define KSTEPS (D_IN / BK)   // 16
#define GEMM_BLOCKS ((N_NODES + BM - 1) / BM)   // 782
#define TOTAL_BLOCKS (GEMM_BLOCKS * 3)          // 2346: 782 gemm + 1564 build

__global__ __launch_bounds__(512) void gemm_build_kernel(
    const float* __restrict__ x, const char* __restrict__ img,
    u16* __restrict__ support,
    const int* __restrict__ ei, const float* __restrict__ ew,
    int* __restrict__ deg, int2* __restrict__ csr) {
  __shared__ u16 Wbuf[2][16384];  // [256 n][64 k] swizzled, 32 KB each
  __shared__ u16 Xbuf[2][4096];   // [64 m][64 k] swizzled,  8 KB each

  const int bid = blockIdx.x;
  if (bid % 3 != 0) {
    // ---------------- build path: one edge per thread ----------------
    const int b = bid - bid / 3 - 1;          // build ordinal 0..1563
    const int e = b * 512 + threadIdx.x;
    if (e < N_EDGES) {
      const int src = ei[e];
      const int dst = ei[N_EDGES + e];
      const float w = ew[e];
      const int slot = atomicAdd(&deg[dst], 1);
      if (slot < CAP) csr[dst * CAP + slot] = make_int2(src, __float_as_int(w));
    }
    return;
  }

  // ---------------- GEMM path (r6 verbatim) ----------------
  const int tid  = threadIdx.x;
  const int lane = tid & 63;
  const int wid  = tid >> 6;
  const int wn   = wid & 3;
  const int wm   = wid >> 2;
  const int l15  = lane & 15;
  const int l16  = lane >> 4;
  const int m0   = (bid / 3) * BM;

  f32x4 acc[4][2];
#pragma unroll
  for (int i = 0; i < 4; ++i)
#pragma unroll
    for (int j = 0; j < 2; ++j) acc[i][j] = (f32x4)0.0f;

  const int xrow = tid >> 3;
  const int xk8  = (tid & 7) * 8;
  const int xrg  = min(m0 + xrow, N_NODES - 1);
  const float* xp = x + (size_t)xrg * D_IN + xk8;
  const int xw_off = swz(xrow * 128 + xk8 * 2);

  int a_off[2][4], b_off[2][2];
#pragma unroll
  for (int ks = 0; ks < 2; ++ks) {
#pragma unroll
    for (int i = 0; i < 4; ++i)
      a_off[ks][i] = swz((wn * 64 + i * 16 + l15) * 128 + ks * 64 + l16 * 16);
#pragma unroll
    for (int j = 0; j < 2; ++j)
      b_off[ks][j] = swz((wm * 32 + j * 16 + l15) * 128 + ks * 64 + l16 * 16);
  }

#pragma unroll
  for (int r = 0; r < 4; ++r)
    gll16(img + r * 8192 + tid * 16, (char*)&Wbuf[0][0] + r * 8192 + tid * 16);
  {
    const float4 xa = *(const float4*)(xp);
    const float4 xb = *(const float4*)(xp + 4);
    bf16x8 xv;
    xv[0] = (short)f2bfu(xa.x); xv[1] = (short)f2bfu(xa.y);
    xv[2] = (short)f2bfu(xa.z); xv[3] = (short)f2bfu(xa.w);
    xv[4] = (short)f2bfu(xb.x); xv[5] = (short)f2bfu(xb.y);
    xv[6] = (short)f2bfu(xb.z); xv[7] = (short)f2bfu(xb.w);
    *(bf16x8*)((char*)&Xbuf[0][0] + xw_off) = xv;
  }
  __syncthreads();

  for (int kt = 0; kt < KSTEPS; ++kt) {
    const int cur = kt & 1;
    float4 xa, xb;
    if (kt < KSTEPS - 1) {
#pragma unroll
      for (int r = 0; r < 4; ++r)
        gll16(img + (size_t)(kt + 1) * 32768 + r * 8192 + tid * 16,
              (char*)&Wbuf[cur ^ 1][0] + r * 8192 + tid * 16);
      xa = *(const float4*)(xp + (kt + 1) * BK);
      xb = *(const float4*)(xp + (kt + 1) * BK + 4);
    }

#pragma unroll
    for (int ks = 0; ks < 2; ++ks) {
      bf16x8 af[4], bfr[2];
#pragma unroll
      for (int i = 0; i < 4; ++i)
        af[i] = *(const bf16x8*)((const char*)&Wbuf[cur][0] + a_off[ks][i]);
#pragma unroll
      for (int j = 0; j < 2; ++j)
        bfr[j] = *(const bf16x8*)((const char*)&Xbuf[cur][0] + b_off[ks][j]);
#pragma unroll
      for (int i = 0; i < 4; ++i)
#pragma unroll
        for (int j = 0; j < 2; ++j)
          acc[i][j] = __builtin_amdgcn_mfma_f32_16x16x32_bf16(af[i], bfr[j], acc[i][j], 0, 0, 0);
    }

    if (kt < KSTEPS - 1) {
      bf16x8 xv;
      xv[0] = (short)f2bfu(xa.x); xv[1] = (short)f2bfu(xa.y);
      xv[2] = (short)f2bfu(xa.z); xv[3] = (short)f2bfu(xa.w);
      xv[4] = (short)f2bfu(xb.x); xv[5] = (short)f2bfu(xb.y);
      xv[6] = (short)f2bfu(xb.z); xv[7] = (short)f2bfu(xb.w);
      *(bf16x8*)((char*)&Xbuf[cur ^ 1][0] + xw_off) = xv;
    }
    __syncthreads();
  }

#pragma unroll
  for (int j = 0; j < 2; ++j) {
    const int m = m0 + wm * 32 + j * 16 + l15;
    if (m < N_NODES) {
#pragma unroll
      for (int i = 0; i < 4; ++i) {
        const int n = wn * 64 + i * 16 + l16 * 4;
        ushort4 o;
        o.x = f2bfu(acc[i][j][0]);
        o.y = f2bfu(acc[i][j][1]);
        o.z = f2bfu(acc[i][j][2]);
        o.w = f2bfu(acc[i][j][3]);
        *(ushort4*)&support[(size_t)m * D_OUT + n] = o;
      }
    }
  }
}

// ---------------------------------------------------------------------------
// Kernel 3: per-node gather-aggregate + epilogue (r5 version, ~20 us).
// ---------------------------------------------------------------------------
__global__ __launch_bounds__(256) void agg_kernel(const u16* __restrict__ support,
                                                  const int* __restrict__ deg,
                                                  const int2* __restrict__ csr,
                                                  const float* __restrict__ norm,
                                                  const float* __restrict__ bias,
                                                  float* __restrict__ out) {
  const int lane = threadIdx.x & 63;
  const int wid  = threadIdx.x >> 6;
  const int node = blockIdx.x * 4 + wid;   // grid 12500 -> exactly 50000
  const int d    = min(deg[node], CAP);
  const int cb   = node * CAP;
  const int ch   = lane * 4;

  float a0 = 0.f, a1 = 0.f, a2 = 0.f, a3 = 0.f;
  int s = 0;

  for (; s + 16 <= d; s += 16) {
    i32x4 q[8];
#pragma unroll
    for (int i = 0; i < 8; ++i)
      q[i] = __builtin_nontemporal_load((const i32x4*)&csr[cb + s + 2 * i]);
    ushort4 v[16];
#pragma unroll
    for (int i = 0; i < 8; ++i) {
      v[2 * i]     = *(const ushort4*)&support[(size_t)q[i][0] * D_OUT + ch];
      v[2 * i + 1] = *(const ushort4*)&support[(size_t)q[i][2] * D_OUT + ch];
    }
#pragma unroll
    for (int i = 0; i < 8; ++i) {
      const float wa = __int_as_float(q[i][1]);
      const float wb = __int_as_float(q[i][3]);
      a0 = fmaf(wa, bfu2f(v[2 * i].x), a0);
      a1 = fmaf(wa, bfu2f(v[2 * i].y), a1);
      a2 = fmaf(wa, bfu2f(v[2 * i].z), a2);
      a3 = fmaf(wa, bfu2f(v[2 * i].w), a3);
      a0 = fmaf(wb, bfu2f(v[2 * i + 1].x), a0);
      a1 = fmaf(wb, bfu2f(v[2 * i + 1].y), a1);
      a2 = fmaf(wb, bfu2f(v[2 * i + 1].z), a2);
      a3 = fmaf(wb, bfu2f(v[2 * i + 1].w), a3);
    }
  }

  for (; s + 8 <= d; s += 8) {
    i32x4 q[4];
#pragma unroll
    for (int i = 0; i < 4; ++i)
      q[i] = __builtin_nontemporal_load((const i32x4*)&csr[cb + s + 2 * i]);
    ushort4 v[8];
#pragma unroll
    for (int i = 0; i < 4; ++i) {
      v[2 * i]     = *(const ushort4*)&support[(size_t)q[i][0] * D_OUT + ch];
      v[2 * i + 1] = *(const ushort4*)&support[(size_t)q[i][2] * D_OUT + ch];
    }
#pragma unroll
    for (int i = 0; i < 4; ++i) {
      const float wa = __int_as_float(q[i][1]);
      const float wb = __int_as_float(q[i][3]);
      a0 = fmaf(wa, bfu2f(v[2 * i].x), a0);
      a1 = fmaf(wa, bfu2f(v[2 * i].y), a1);
      a2 = fmaf(wa, bfu2f(v[2 * i].z), a2);
      a3 = fmaf(wa, bfu2f(v[2 * i].w), a3);
      a0 = fmaf(wb, bfu2f(v[2 * i + 1].x), a0);
      a1 = fmaf(wb, bfu2f(v[2 * i + 1].y), a1);
      a2 = fmaf(wb, bfu2f(v[2 * i + 1].z), a2);
      a3 = fmaf(wb, bfu2f(v[2 * i + 1].w), a3);
    }
  }

  for (; s < d; ++s) {
    const int2  e   = csr[cb + s];
    const float wgt = __int_as_float(e.y);
    const ushort4 v = *(const ushort4*)&support[(size_t)e.x * D_OUT + ch];
    a0 = fmaf(wgt, bfu2f(v.x), a0);
    a1 = fmaf(wgt, bfu2f(v.y), a1);
    a2 = fmaf(wgt, bfu2f(v.z), a2);
    a3 = fmaf(wgt, bfu2f(v.w), a3);
  }

  const float rn = 1.0f / norm[node];
  const float4 b = *(const float4*)&bias[ch];
  float o0 = fmaf(a0, rn, b.x);
  float o1 = fmaf(a1, rn, b.y);
  float o2 = fmaf(a2, rn, b.z);
  float o3 = fmaf(a3, rn, b.w);
  o0 = o0 > 0.f ? o0 : o0 * LEAKY;
  o1 = o1 > 0.f ? o1 : o1 * LEAKY;
  o2 = o2 > 0.f ? o2 : o2 * LEAKY;
  o3 = o3 > 0.f ? o3 : o3 * LEAKY;
  f32x4 ov;
  ov[0] = o0; ov[1] = o1; ov[2] = o2; ov[3] = o3;
  __builtin_nontemporal_store(ov, (f32x4*)&out[(size_t)node * D_OUT + ch]);
}

// ---------------------------------------------------------------------------
// ws layout (bytes):
//   support  bf16  [50000][256]     @ 0          25,600,000
//   Wimg     bf16  16x[256][64] swz @ 25,600,000    524,288
//   csr      int2  [50000][64]      @ 26,124,288 25,600,000
//   deg      int   [50000]          @ 51,724,288    200,000
// ---------------------------------------------------------------------------
extern "C" void kernel_launch(void* const* d_in, const int* in_sizes, int n_in,
                              void* d_out, int out_size, void* d_ws, size_t ws_size,
                              hipStream_t stream) {
  const float* x    = (const float*)d_in[0];
  const float* w    = (const float*)d_in[1];
  const float* bias = (const float*)d_in[2];
  const int*   ei   = (const int*)d_in[3];
  const float* ew   = (const float*)d_in[4];
  const float* norm = (const float*)d_in[5];
  float* out = (float*)d_out;

  char* ws = (char*)d_ws;
  u16*   support = (u16*)  (ws);
  char*  img     =         (ws + 25600000);
  int2*  csr     = (int2*) (ws + 26124288);
  int*   deg     = (int*)  (ws + 51724288);

  wconv_kernel<<<128, 256, 0, stream>>>(w, img, deg);
  gemm_build_kernel<<<TOTAL_BLOCKS, 512, 0, stream>>>(
      x, img, support, ei, ew, deg, csr);
  agg_kernel<<<N_NODES / 4, 256, 0, stream>>>(support, deg, csr, norm, bias, out);
}

// Round 14
// 151.893 us; speedup vs baseline: 1.8104x; 1.0495x over previous
//
#include <hip/hip_runtime.h>
#include <hip/hip_bf16.h>

#define N_NODES 50000
#define N_EDGES 800000
#define D_IN    1024
#define D_OUT   256
#define CAP     64
#define LEAKY   0.01f

typedef __attribute__((ext_vector_type(8))) short bf16x8;
typedef __attribute__((ext_vector_type(4))) float f32x4;
typedef __attribute__((ext_vector_type(4))) int   i32x4;
typedef unsigned short u16;

__device__ __forceinline__ u16 f2bfu(float f) {
  uint32_t x = __float_as_uint(f);
  uint32_t r = (x + 0x7FFFu + ((x >> 16) & 1u)) >> 16;  // RNE
  return (u16)r;
}
__device__ __forceinline__ float bfu2f(u16 u) {
  return __uint_as_float(((uint32_t)u) << 16);
}
// XOR bank swizzle: flip byte bits 4-6 with row (byte>>7) low bits.
__device__ __forceinline__ int swz(int b) { return b ^ (((b >> 7) & 7) << 4); }

__device__ __forceinline__ void gll16(const void* g, void* l) {
  __builtin_amdgcn_global_load_lds(
      (const __attribute__((address_space(1))) uint32_t*)g,
      (__attribute__((address_space(3))) uint32_t*)l, 16, 0, 0);
}

// ---------------------------------------------------------------------------
// Kernel 1: weight fp32 [1024][256] -> bf16 swizzled image,
// 16 k-tiles x [256 n][64 k] x 32768 B. Also zeroes deg[]. Coalesced reads.
// ---------------------------------------------------------------------------
__global__ __launch_bounds__(256) void wconv_kernel(const float* __restrict__ w,
                                                    char* __restrict__ img,
                                                    int* __restrict__ deg) {
  const int t   = blockIdx.x * 256 + threadIdx.x;   // 0..32767
  if (t < N_NODES) deg[t] = 0;
  const int t2 = t + 32768;
  if (t2 < N_NODES) deg[t2] = 0;

  const int n   = t & 255;
  const int kc  = (t >> 8) * 8;
  const int kt  = kc >> 6;
  const int kin = kc & 63;
  bf16x8 v;
#pragma unroll
  for (int i = 0; i < 8; ++i) v[i] = (short)f2bfu(w[(size_t)(kc + i) * D_OUT + n]);
  *(bf16x8*)(img + kt * 32768 + swz(n * 128 + kin * 2)) = v;
}

// ---------------------------------------------------------------------------
// Kernel 2 (FUSED, r6 exact — session best 150.1 us total): 64 grid-stride
// build blocks + 782 GEMM blocks. GEMM: BM=64, BN=256, BK=64, 8 waves,
// double-buffered LDS, W via global_load_lds from the swizzled image,
// X reg-staged + swizzled ds_write. Measured thrice at ~121 us; 7 structural
// alternatives (r7/r8/r10/r12/r13) all >= this. At 222 TF on this skinny
// shape (N=256, 16-step K-loop) it exceeds the verified m97-ladder's
// small-N reference curve (18 TF @N=512, 90 @N=1024) — structural floor.
// ---------------------------------------------------------------------------
#define BM 64
#define BK 64
#define KSTEPS (D_IN / BK)   // 16
#define GEMM_BLOCKS ((N_NODES + BM - 1) / BM)   // 782
#define BUILD_BLOCKS 64

__global__ __launch_bounds__(512) void gemm_build_kernel(
    const float* __restrict__ x, const char* __restrict__ img,
    u16* __restrict__ support,
    const int* __restrict__ ei, const float* __restrict__ ew,
    int* __restrict__ deg, int2* __restrict__ csr) {
  __shared__ u16 Wbuf[2][16384];  // [256 n][64 k] swizzled, 32 KB each
  __shared__ u16 Xbuf[2][4096];   // [64 m][64 k] swizzled,  8 KB each

  if (blockIdx.x < BUILD_BLOCKS) {
    const int t0 = blockIdx.x * 512 + threadIdx.x;
    for (int e = t0; e < N_EDGES; e += BUILD_BLOCKS * 512) {
      const int src = ei[e];
      const int dst = ei[N_EDGES + e];
      const float w = ew[e];
      const int slot = atomicAdd(&deg[dst], 1);
      if (slot < CAP) csr[dst * CAP + slot] = make_int2(src, __float_as_int(w));
    }
    return;
  }

  const int tid  = threadIdx.x;
  const int lane = tid & 63;
  const int wid  = tid >> 6;
  const int wn   = wid & 3;
  const int wm   = wid >> 2;
  const int l15  = lane & 15;
  const int l16  = lane >> 4;
  const int m0   = (blockIdx.x - BUILD_BLOCKS) * BM;

  f32x4 acc[4][2];
#pragma unroll
  for (int i = 0; i < 4; ++i)
#pragma unroll
    for (int j = 0; j < 2; ++j) acc[i][j] = (f32x4)0.0f;

  const int xrow = tid >> 3;
  const int xk8  = (tid & 7) * 8;
  const int xrg  = min(m0 + xrow, N_NODES - 1);
  const float* xp = x + (size_t)xrg * D_IN + xk8;
  const int xw_off = swz(xrow * 128 + xk8 * 2);

  int a_off[2][4], b_off[2][2];
#pragma unroll
  for (int ks = 0; ks < 2; ++ks) {
#pragma unroll
    for (int i = 0; i < 4; ++i)
      a_off[ks][i] = swz((wn * 64 + i * 16 + l15) * 128 + ks * 64 + l16 * 16);
#pragma unroll
    for (int j = 0; j < 2; ++j)
      b_off[ks][j] = swz((wm * 32 + j * 16 + l15) * 128 + ks * 64 + l16 * 16);
  }

#pragma unroll
  for (int r = 0; r < 4; ++r)
    gll16(img + r * 8192 + tid * 16, (char*)&Wbuf[0][0] + r * 8192 + tid * 16);
  {
    const float4 xa = *(const float4*)(xp);
    const float4 xb = *(const float4*)(xp + 4);
    bf16x8 xv;
    xv[0] = (short)f2bfu(xa.x); xv[1] = (short)f2bfu(xa.y);
    xv[2] = (short)f2bfu(xa.z); xv[3] = (short)f2bfu(xa.w);
    xv[4] = (short)f2bfu(xb.x); xv[5] = (short)f2bfu(xb.y);
    xv[6] = (short)f2bfu(xb.z); xv[7] = (short)f2bfu(xb.w);
    *(bf16x8*)((char*)&Xbuf[0][0] + xw_off) = xv;
  }
  __syncthreads();

  for (int kt = 0; kt < KSTEPS; ++kt) {
    const int cur = kt & 1;
    float4 xa, xb;
    if (kt < KSTEPS - 1) {
#pragma unroll
      for (int r = 0; r < 4; ++r)
        gll16(img + (size_t)(kt + 1) * 32768 + r * 8192 + tid * 16,
              (char*)&Wbuf[cur ^ 1][0] + r * 8192 + tid * 16);
      xa = *(const float4*)(xp + (kt + 1) * BK);
      xb = *(const float4*)(xp + (kt + 1) * BK + 4);
    }

#pragma unroll
    for (int ks = 0; ks < 2; ++ks) {
      bf16x8 af[4], bfr[2];
#pragma unroll
      for (int i = 0; i < 4; ++i)
        af[i] = *(const bf16x8*)((const char*)&Wbuf[cur][0] + a_off[ks][i]);
#pragma unroll
      for (int j = 0; j < 2; ++j)
        bfr[j] = *(const bf16x8*)((const char*)&Xbuf[cur][0] + b_off[ks][j]);
#pragma unroll
      for (int i = 0; i < 4; ++i)
#pragma unroll
        for (int j = 0; j < 2; ++j)
          acc[i][j] = __builtin_amdgcn_mfma_f32_16x16x32_bf16(af[i], bfr[j], acc[i][j], 0, 0, 0);
    }

    if (kt < KSTEPS - 1) {
      bf16x8 xv;
      xv[0] = (short)f2bfu(xa.x); xv[1] = (short)f2bfu(xa.y);
      xv[2] = (short)f2bfu(xa.z); xv[3] = (short)f2bfu(xa.w);
      xv[4] = (short)f2bfu(xb.x); xv[5] = (short)f2bfu(xb.y);
      xv[6] = (short)f2bfu(xb.z); xv[7] = (short)f2bfu(xb.w);
      *(bf16x8*)((char*)&Xbuf[cur ^ 1][0] + xw_off) = xv;
    }
    __syncthreads();
  }

#pragma unroll
  for (int j = 0; j < 2; ++j) {
    const int m = m0 + wm * 32 + j * 16 + l15;
    if (m < N_NODES) {
#pragma unroll
      for (int i = 0; i < 4; ++i) {
        const int n = wn * 64 + i * 16 + l16 * 4;
        ushort4 o;
        o.x = f2bfu(acc[i][j][0]);
        o.y = f2bfu(acc[i][j][1]);
        o.z = f2bfu(acc[i][j][2]);
        o.w = f2bfu(acc[i][j][3]);
        *(ushort4*)&support[(size_t)m * D_OUT + n] = o;
      }
    }
  }
}

// ---------------------------------------------------------------------------
// Kernel 3: per-node gather-aggregate + epilogue. One wave per node,
// 16-deep gather pipeline (~20 us measured).
// ---------------------------------------------------------------------------
__global__ __launch_bounds__(256) void agg_kernel(const u16* __restrict__ support,
                                                  const int* __restrict__ deg,
                                                  const int2* __restrict__ csr,
                                                  const float* __restrict__ norm,
                                                  const float* __restrict__ bias,
                                                  float* __restrict__ out) {
  const int lane = threadIdx.x & 63;
  const int wid  = threadIdx.x >> 6;
  const int node = blockIdx.x * 4 + wid;   // grid 12500 -> exactly 50000
  const int d    = min(deg[node], CAP);
  const int cb   = node * CAP;
  const int ch   = lane * 4;

  float a0 = 0.f, a1 = 0.f, a2 = 0.f, a3 = 0.f;
  int s = 0;

  for (; s + 16 <= d; s += 16) {
    i32x4 q[8];
#pragma unroll
    for (int i = 0; i < 8; ++i)
      q[i] = __builtin_nontemporal_load((const i32x4*)&csr[cb + s + 2 * i]);
    ushort4 v[16];
#pragma unroll
    for (int i = 0; i < 8; ++i) {
      v[2 * i]     = *(const ushort4*)&support[(size_t)q[i][0] * D_OUT + ch];
      v[2 * i + 1] = *(const ushort4*)&support[(size_t)q[i][2] * D_OUT + ch];
    }
#pragma unroll
    for (int i = 0; i < 8; ++i) {
      const float wa = __int_as_float(q[i][1]);
      const float wb = __int_as_float(q[i][3]);
      a0 = fmaf(wa, bfu2f(v[2 * i].x), a0);
      a1 = fmaf(wa, bfu2f(v[2 * i].y), a1);
      a2 = fmaf(wa, bfu2f(v[2 * i].z), a2);
      a3 = fmaf(wa, bfu2f(v[2 * i].w), a3);
      a0 = fmaf(wb, bfu2f(v[2 * i + 1].x), a0);
      a1 = fmaf(wb, bfu2f(v[2 * i + 1].y), a1);
      a2 = fmaf(wb, bfu2f(v[2 * i + 1].z), a2);
      a3 = fmaf(wb, bfu2f(v[2 * i + 1].w), a3);
    }
  }

  for (; s + 8 <= d; s += 8) {
    i32x4 q[4];
#pragma unroll
    for (int i = 0; i < 4; ++i)
      q[i] = __builtin_nontemporal_load((const i32x4*)&csr[cb + s + 2 * i]);
    ushort4 v[8];
#pragma unroll
    for (int i = 0; i < 4; ++i) {
      v[2 * i]     = *(const ushort4*)&support[(size_t)q[i][0] * D_OUT + ch];
      v[2 * i + 1] = *(const ushort4*)&support[(size_t)q[i][2] * D_OUT + ch];
    }
#pragma unroll
    for (int i = 0; i < 4; ++i) {
      const float wa = __int_as_float(q[i][1]);
      const float wb = __int_as_float(q[i][3]);
      a0 = fmaf(wa, bfu2f(v[2 * i].x), a0);
      a1 = fmaf(wa, bfu2f(v[2 * i].y), a1);
      a2 = fmaf(wa, bfu2f(v[2 * i].z), a2);
      a3 = fmaf(wa, bfu2f(v[2 * i].w), a3);
      a0 = fmaf(wb, bfu2f(v[2 * i + 1].x), a0);
      a1 = fmaf(wb, bfu2f(v[2 * i + 1].y), a1);
      a2 = fmaf(wb, bfu2f(v[2 * i + 1].z), a2);
      a3 = fmaf(wb, bfu2f(v[2 * i + 1].w), a3);
    }
  }

  for (; s < d; ++s) {
    const int2  e   = csr[cb + s];
    const float wgt = __int_as_float(e.y);
    const ushort4 v = *(const ushort4*)&support[(size_t)e.x * D_OUT + ch];
    a0 = fmaf(wgt, bfu2f(v.x), a0);
    a1 = fmaf(wgt, bfu2f(v.y), a1);
    a2 = fmaf(wgt, bfu2f(v.z), a2);
    a3 = fmaf(wgt, bfu2f(v.w), a3);
  }

  const float rn = 1.0f / norm[node];
  const float4 b = *(const float4*)&bias[ch];
  float o0 = fmaf(a0, rn, b.x);
  float o1 = fmaf(a1, rn, b.y);
  float o2 = fmaf(a2, rn, b.z);
  float o3 = fmaf(a3, rn, b.w);
  o0 = o0 > 0.f ? o0 : o0 * LEAKY;
  o1 = o1 > 0.f ? o1 : o1 * LEAKY;
  o2 = o2 > 0.f ? o2 : o2 * LEAKY;
  o3 = o3 > 0.f ? o3 : o3 * LEAKY;
  f32x4 ov;
  ov[0] = o0; ov[1] = o1; ov[2] = o2; ov[3] = o3;
  __builtin_nontemporal_store(ov, (f32x4*)&out[(size_t)node * D_OUT + ch]);
}

// ---------------------------------------------------------------------------
// ws layout (bytes):
//   support  bf16  [50000][256]     @ 0          25,600,000
//   Wimg     bf16  16x[256][64] swz @ 25,600,000    524,288
//   csr      int2  [50000][64]      @ 26,124,288 25,600,000
//   deg      int   [50000]          @ 51,724,288    200,000
// ---------------------------------------------------------------------------
extern "C" void kernel_launch(void* const* d_in, const int* in_sizes, int n_in,
                              void* d_out, int out_size, void* d_ws, size_t ws_size,
                              hipStream_t stream) {
  const float* x    = (const float*)d_in[0];
  const float* w    = (const float*)d_in[1];
  const float* bias = (const float*)d_in[2];
  const int*   ei   = (const int*)d_in[3];
  const float* ew   = (const float*)d_in[4];
  const float* norm = (const float*)d_in[5];
  float* out = (float*)d_out;

  char* ws = (char*)d_ws;
  u16*   support = (u16*)  (ws);
  char*  img     =         (ws + 25600000);
  int2*  csr     = (int2*) (ws + 26124288);
  int*   deg     = (int*)  (ws + 51724288);

  wconv_kernel<<<128, 256, 0, stream>>>(w, img, deg);
  gemm_build_kernel<<<BUILD_BLOCKS + GEMM_BLOCKS, 512, 0, stream>>>(
      x, img, support, ei, ew, deg, csr);
  agg_kernel<<<N_NODES / 4, 256, 0, stream>>>(support, deg, csr, norm, bias, out);
}